// Round 12
// baseline (742.471 us; speedup 1.0000x reference)
//
#include <hip/hip_runtime.h>
#include <hip/hip_bf16.h>

#define Hd 128
#define Nn 50000
#define Ee 400000
#define Bb 2
#define NROWS 100000          // B*N flat node rows
#define TPB2 3125             // 128-edge tiles per batch
#define NT2 6250              // total 128-edge tiles

typedef __attribute__((ext_vector_type(8))) short bf16x8;
typedef __attribute__((ext_vector_type(4))) short bf16x4;
typedef __attribute__((ext_vector_type(4))) float f32x4;

static __device__ __forceinline__ short f2bf(float f) {
    __hip_bfloat16 h = __float2bfloat16(f);
    return *reinterpret_cast<short*>(&h);
}
static __device__ __forceinline__ float bf2f(short s) {
    union { unsigned u; float f; } v; v.u = ((unsigned)(unsigned short)s) << 16;
    return v.f;
}
static __device__ __forceinline__ bf16x8 cvt8(float4 a, float4 b) {
    bf16x8 r;
    r[0] = f2bf(a.x); r[1] = f2bf(a.y); r[2] = f2bf(a.z); r[3] = f2bf(a.w);
    r[4] = f2bf(b.x); r[5] = f2bf(b.y); r[6] = f2bf(b.z); r[7] = f2bf(b.w);
    return r;
}
static __device__ __forceinline__ unsigned pk2(float a, float b) {
    return (unsigned)(unsigned short)f2bf(a) | ((unsigned)(unsigned short)f2bf(b) << 16);
}
// LDS-only barrier: does NOT drain vmcnt.
static __device__ __forceinline__ void lds_barrier() {
    asm volatile("s_waitcnt lgkmcnt(0)" ::: "memory");
    __builtin_amdgcn_s_barrier();
}

// wbuf layout (shorts): WabT[256][128] @0 | W1cT[128][128] @32768 | W2T[128][128] @49152
//                       Wn1T[128][256] @65536 | Wn2T[128][128] @98304   (total 114688)
__global__ void prep_weights(const float* __restrict__ We1, const float* __restrict__ We2,
                             const float* __restrict__ Wn1, const float* __restrict__ Wn2,
                             short* __restrict__ wbuf) {
    int gid = blockIdx.x * 256 + threadIdx.x;
    if (gid < 32768) {
        int c = gid >> 7, k = gid & 127;
        float v = (c < 128) ? We1[k * 128 + c] : We1[(k + 128) * 128 + (c - 128)];
        wbuf[gid] = f2bf(v); return;
    }
    int g = gid - 32768;
    if (g < 16384) { int c = g >> 7, k = g & 127; wbuf[gid] = f2bf(We1[(k + 256) * 128 + c]); return; }
    g -= 16384;
    if (g < 16384) { int c = g >> 7, k = g & 127; wbuf[gid] = f2bf(We2[k * 128 + c]); return; }
    g -= 16384;
    if (g < 32768) { int c = g >> 8, k = g & 255; wbuf[gid] = f2bf(Wn1[k * 128 + c]); return; }
    g -= 32768;
    if (g < 16384) { int c = g >> 7, k = g & 127; wbuf[gid] = f2bf(Wn2[k * 128 + c]); }
}

// ---- CSR by dest (elist = edge ids sorted by dest) ----
__global__ void hist_kernel(const int* __restrict__ ei, int* __restrict__ cnt) {
    int t = blockIdx.x * 256 + threadIdx.x;
    if (t < Ee) atomicAdd(&cnt[ei[Ee + t]], 1);
}
__global__ void scan1(const int* __restrict__ cnt, int* __restrict__ cur, int* __restrict__ part) {
    __shared__ int s[256];
    int i = blockIdx.x * 256 + threadIdx.x;
    int v = (i < Nn) ? cnt[i] : 0;
    s[threadIdx.x] = v; __syncthreads();
    #pragma unroll
    for (int off = 1; off < 256; off <<= 1) {
        int u = (threadIdx.x >= off) ? s[threadIdx.x - off] : 0;
        __syncthreads(); s[threadIdx.x] += u; __syncthreads();
    }
    if (i < Nn) cur[i] = s[threadIdx.x] - v;
    if (threadIdx.x == 255) part[blockIdx.x] = s[255];
}
__global__ void scan2(int* __restrict__ part) {
    if (threadIdx.x == 0 && blockIdx.x == 0) {
        int run = 0;
        for (int i = 0; i < 196; i++) { int t = part[i]; part[i] = run; run += t; }
    }
}
__global__ void scan3(int* __restrict__ cur, const int* __restrict__ part) {
    int i = blockIdx.x * 256 + threadIdx.x;
    if (i < Nn) cur[i] += part[blockIdx.x];
}
__global__ void scatter_k(const int* __restrict__ ei, int* __restrict__ cur, int* __restrict__ elist) {
    int t = blockIdx.x * 256 + threadIdx.x;
    if (t < Ee) { int d = ei[Ee + t]; int pos = atomicAdd(&cur[d], 1); elist[pos] = t; }
}

// ---- node_pre: xa = x@W1a, xb = x@W1b (bf16 out, no bias) ----
__global__ __launch_bounds__(256) void node_pre(
    const float* __restrict__ x, const short* __restrict__ WabT,
    short* __restrict__ xa, short* __restrict__ xb)
{
    __shared__ __align__(16) short X[32 * 128];

    const int nbase = blockIdx.x * 32;
    const int t = threadIdx.x;
    const int wv = t >> 6, lane = t & 63;
    const int row16 = lane & 15, kg = lane >> 4;

    {
        int g = t >> 3, q = t & 7;
        const float* src = x + ((size_t)(nbase + g)) * Hd + q * 16;
        float4 a0 = ((const float4*)src)[0], a1 = ((const float4*)src)[1];
        float4 a2 = ((const float4*)src)[2], a3 = ((const float4*)src)[3];
        ((bf16x8*)X)[g * 16 + ((q * 2) ^ (g & 7))]     = cvt8(a0, a1);
        ((bf16x8*)X)[g * 16 + ((q * 2 + 1) ^ (g & 7))] = cvt8(a2, a3);
    }

    bf16x8 wf[4][4];
    #pragma unroll
    for (int nt = 0; nt < 4; nt++) {
        int n = wv * 64 + nt * 16 + row16;
        #pragma unroll
        for (int kt = 0; kt < 4; kt++)
            wf[kt][nt] = *(const bf16x8*)(WabT + n * 128 + kt * 32 + kg * 8);
    }
    __syncthreads();

    f32x4 acc[2][4];
    #pragma unroll
    for (int mt = 0; mt < 2; mt++)
        #pragma unroll
        for (int nt = 0; nt < 4; nt++) acc[mt][nt] = (f32x4){0.f,0.f,0.f,0.f};

    #pragma unroll
    for (int mt = 0; mt < 2; mt++) {
        int row = mt * 16 + row16;
        #pragma unroll
        for (int kt = 0; kt < 4; kt++) {
            bf16x8 xf = ((const bf16x8*)X)[row * 16 + ((kt * 4 + kg) ^ (row & 7))];
            #pragma unroll
            for (int nt = 0; nt < 4; nt++)
                acc[mt][nt] = __builtin_amdgcn_mfma_f32_16x16x32_bf16(wf[kt][nt], xf, acc[mt][nt], 0, 0, 0);
        }
    }

    #pragma unroll
    for (int mt = 0; mt < 2; mt++) {
        size_t node = nbase + mt * 16 + row16;
        #pragma unroll
        for (int nt = 0; nt < 4; nt++) {
            int ch = wv * 64 + nt * 16 + kg * 4;
            uint2 pk = { pk2(acc[mt][nt][0], acc[mt][nt][1]), pk2(acc[mt][nt][2], acc[mt][nt][3]) };
            short* dst = (ch < 128) ? (xa + node * Hd + ch) : (xb + node * Hd + (ch - 128));
            *(uint2*)dst = pk;
        }
    }
}

// ---- edge_mlp: 128-edge DEST-SORTED tiles, r10 wave structure (8 waves x 16 cols),
//      ONE 32KB LDS region aliased Aea -> A2 -> et(bf16)  => 4 blocks/CU.
__global__ __launch_bounds__(512, 8) void edge_mlp(
    const float* __restrict__ ea, const int* __restrict__ ei,
    const int* __restrict__ elist,
    const short* __restrict__ xa, const short* __restrict__ xb,
    const short* __restrict__ W1cT, const float* __restrict__ be1,
    const short* __restrict__ W2T, const float* __restrict__ be2,
    float* __restrict__ e_out, float* __restrict__ agg)
{
    __shared__ __align__(16) char smem[32768 + 1536];   // one aliased 32K region + idx
    short* Abuf = (short*)smem;                    // [128 rows][16 groups] — Aea, then A2, then et(bf16)
    int* ol = (int*)(smem + 32768);                // [128]
    int* sl = ol + 128;
    int* dl = sl + 128;

    const int tile = blockIdx.x;
    const int b = tile / TPB2;
    const int w0 = (tile % TPB2) * 128;
    const int t = threadIdx.x;
    const int wv = t >> 6, lane = t & 63;
    const int row16 = lane & 15, kg = lane >> 4;
    const int n0 = wv * 16 + kg * 4;        // this lane's 4 output channels
    const int sr = t >> 3, sq = t & 7;      // staging: row, 64B quarter

    if (t < 128) {
        int o = elist[w0 + t];
        ol[t] = o; sl[t] = ei[o]; dl[t] = ei[Ee + o];
    }
    __syncthreads();

    // per-thread row indices for its 8 MFMA rows
    int on[8], sn[8], dn[8];
    #pragma unroll
    for (int mt = 0; mt < 8; mt++) {
        int r = mt * 16 + row16;
        on[mt] = ol[r]; sn[mt] = sl[r]; dn[mt] = dl[r];
    }

    // stage ea tile: 2 rows per thread (gathered 512B rows, 8 thr x 64B each)
    #pragma unroll
    for (int h = 0; h < 2; h++) {
        int row = sr + h * 64;
        const float* src = ea + ((size_t)b * Ee + ol[row]) * Hd + sq * 16;
        float4 a0 = ((const float4*)src)[0], a1 = ((const float4*)src)[1];
        float4 a2 = ((const float4*)src)[2], a3 = ((const float4*)src)[3];
        ((bf16x8*)Abuf)[row * 16 + ((sq * 2) ^ (row & 7))]     = cvt8(a0, a1);
        ((bf16x8*)Abuf)[row * 16 + ((sq * 2 + 1) ^ (row & 7))] = cvt8(a2, a3);
    }

    bf16x8 w1[4], w2[4];
    {
        const short* wp1 = W1cT + (wv * 16 + row16) * 128 + kg * 8;
        const short* wp2 = W2T  + (wv * 16 + row16) * 128 + kg * 8;
        #pragma unroll
        for (int kt = 0; kt < 4; kt++) {
            w1[kt] = *(const bf16x8*)(wp1 + kt * 32);
            w2[kt] = *(const bf16x8*)(wp2 + kt * 32);
        }
    }
    // xa/xb gathers (xb dest-sorted -> cache-hot); issued early, consumed in epilogue
    bf16x4 av[8], bv[8];
    #pragma unroll
    for (int mt = 0; mt < 8; mt++) {
        av[mt] = *(const bf16x4*)(xa + ((size_t)b * Nn + sn[mt]) * Hd + n0);
        bv[mt] = *(const bf16x4*)(xb + ((size_t)b * Nn + dn[mt]) * Hd + n0);
    }
    const float4 b1v = *(const float4*)(be1 + n0);
    const float4 b2v = *(const float4*)(be2 + n0);
    lds_barrier();

    // L1 GEMM: 32 MFMA (reads Aea)
    f32x4 acc[8];
    #pragma unroll
    for (int mt = 0; mt < 8; mt++) acc[mt] = (f32x4){0.f,0.f,0.f,0.f};
    #pragma unroll
    for (int kt = 0; kt < 4; kt++) {
        #pragma unroll
        for (int mt = 0; mt < 8; mt++) {
            int row = mt * 16 + row16;
            bf16x8 af = ((const bf16x8*)Abuf)[row * 16 + ((kt * 4 + kg) ^ (row & 7))];
            acc[mt] = __builtin_amdgcn_mfma_f32_16x16x32_bf16(w1[kt], af, acc[mt], 0, 0, 0);
        }
    }
    lds_barrier();   // all Aea reads complete -> region may be rewritten as A2

    // epilogue: bias + skip adds + relu -> A2 (bf16 swizzled, same region)
    #pragma unroll
    for (int mt = 0; mt < 8; mt++) {
        int row = mt * 16 + row16;
        float vv[4];
        #pragma unroll
        for (int r = 0; r < 4; r++) {
            float u = acc[mt][r] + b1v[r] + bf2f(av[mt][r]) + bf2f(bv[mt][r]);
            vv[r] = u > 0.f ? u : 0.f;
        }
        int G = (n0 >> 3) ^ (row & 7);
        *(uint2*)((char*)Abuf + row * 256 + G * 16 + (n0 & 7) * 2) =
            (uint2){ pk2(vv[0], vv[1]), pk2(vv[2], vv[3]) };
    }
    lds_barrier();

    // L2 GEMM: 32 MFMA (reads A2)
    f32x4 acc2[8];
    #pragma unroll
    for (int mt = 0; mt < 8; mt++) acc2[mt] = (f32x4){0.f,0.f,0.f,0.f};
    #pragma unroll
    for (int kt = 0; kt < 4; kt++) {
        #pragma unroll
        for (int mt = 0; mt < 8; mt++) {
            int row = mt * 16 + row16;
            bf16x8 hf = *(const bf16x8*)((const char*)Abuf + row * 256 + (((kt * 4 + kg) ^ (row & 7)) * 16));
            acc2[mt] = __builtin_amdgcn_mfma_f32_16x16x32_bf16(w2[kt], hf, acc2[mt], 0, 0, 0);
        }
    }

    // finalize e = acc2 + b2; store to e_out (scattered 16B, fire-and-forget)
    #pragma unroll
    for (int mt = 0; mt < 8; mt++) {
        acc2[mt][0] += b2v.x; acc2[mt][1] += b2v.y;
        acc2[mt][2] += b2v.z; acc2[mt][3] += b2v.w;
        float4 ov = { acc2[mt][0], acc2[mt][1], acc2[mt][2], acc2[mt][3] };
        *(float4*)(e_out + ((size_t)b * Ee + on[mt]) * Hd + n0) = ov;
    }
    lds_barrier();   // all A2 reads complete -> region may be rewritten as et

    // restage e-tile as bf16 into et[128][128] (16B-group swizzle), same region
    #pragma unroll
    for (int mt = 0; mt < 8; mt++) {
        int row = mt * 16 + row16;
        int G = (n0 >> 3) ^ (row & 7);
        *(uint2*)((char*)Abuf + row * 256 + G * 16 + (n0 & 7) * 2) =
            (uint2){ pk2(acc2[mt][0], acc2[mt][1]), pk2(acc2[mt][2], acc2[mt][3]) };
    }
    lds_barrier();

    // segment-sum over sorted dests -> few atomics. thread owns channel c, 32-row group.
    {
        int c = t & 127, rg2 = t >> 7;
        int gc = c >> 3, sub = (c & 7) * 2;
        int base = rg2 * 32;
        float s = 0.f;
        int pd = dl[base];
        #pragma unroll
        for (int i = 0; i < 32; i++) {
            int row = base + i;
            float v = bf2f(*(const short*)((const char*)Abuf + row * 256 + ((gc ^ (row & 7)) << 4) + sub));
            int d = dl[row];
            if (d != pd) {
                unsafeAtomicAdd(agg + ((size_t)b * Nn + pd) * Hd + c, s);
                s = 0.f; pd = d;
            }
            s += v;
        }
        unsafeAtomicAdd(agg + ((size_t)b * Nn + pd) * Hd + c, s);
    }
}

// ---- node_mlp (streaming): x_out = relu(concat(x, agg) @ Wn1 + bn1) @ Wn2 + bn2 ----
__global__ __launch_bounds__(512, 4) void node_mlp(
    const float* __restrict__ x, const float* __restrict__ agg,
    const short* __restrict__ Wn1T, const float* __restrict__ bn1,
    const short* __restrict__ Wn2T, const float* __restrict__ bn2,
    float* __restrict__ xout)
{
    __shared__ __align__(16) short A[32 * 256];      // 16KB: [node][32 groups] (x | agg)
    __shared__ __align__(16) short A2[32 * 128];     // 8KB hidden

    const int tilesPerB = (Nn + 31) / 32;            // 1563
    const int bid = blockIdx.x;
    const int b = bid / tilesPerB;
    const int nbase = (bid % tilesPerB) * 32;
    const int t = threadIdx.x;
    const int wv = t >> 6, lane = t & 63;
    const int row16 = lane & 15, kg = lane >> 4;
    const int n0 = wv * 16 + kg * 4;

    {
        int g = t >> 4, q2 = t & 15;
        int n = nbase + g;
        float4 xv0 = {0,0,0,0}, xv1 = xv0;
        float4 s0 = {0,0,0,0}, s1 = s0;
        if (n < Nn) {
            const float* xr = x + ((size_t)b * Nn + n) * Hd + q2 * 8;
            xv0 = ((const float4*)xr)[0]; xv1 = ((const float4*)xr)[1];
            const float* ar = agg + ((size_t)b * Nn + n) * Hd + q2 * 8;
            s0 = ((const float4*)ar)[0]; s1 = ((const float4*)ar)[1];
        }
        ((bf16x8*)A)[g * 32 + (q2 ^ (g & 7))]        = cvt8(xv0, xv1);
        ((bf16x8*)A)[g * 32 + ((16 + q2) ^ (g & 7))] = cvt8(s0, s1);
    }

    bf16x8 w1[8];
    {
        const short* wp = Wn1T + (wv * 16 + row16) * 256 + kg * 8;
        #pragma unroll
        for (int kt = 0; kt < 8; kt++) w1[kt] = *(const bf16x8*)(wp + kt * 32);
    }
    __syncthreads();

    f32x4 acc[2];
    acc[0] = (f32x4){0.f,0.f,0.f,0.f}; acc[1] = (f32x4){0.f,0.f,0.f,0.f};
    #pragma unroll
    for (int kt = 0; kt < 8; kt++) {
        #pragma unroll
        for (int mt = 0; mt < 2; mt++) {
            int row = mt * 16 + row16;
            bf16x8 af = ((const bf16x8*)A)[row * 32 + ((kt * 4 + kg) ^ (row & 7))];
            acc[mt] = __builtin_amdgcn_mfma_f32_16x16x32_bf16(w1[kt], af, acc[mt], 0, 0, 0);
        }
    }

    float4 b1v = *(const float4*)(bn1 + n0);
    bf16x8 w2[4];
    {
        const short* wp = Wn2T + (wv * 16 + row16) * 128 + kg * 8;
        #pragma unroll
        for (int kt = 0; kt < 4; kt++) w2[kt] = *(const bf16x8*)(wp + kt * 32);
    }

    #pragma unroll
    for (int mt = 0; mt < 2; mt++) {
        int row = mt * 16 + row16;
        float v[4];
        #pragma unroll
        for (int r = 0; r < 4; r++) {
            float u = acc[mt][r] + b1v[r];
            v[r] = u > 0.f ? u : 0.f;
        }
        int G = (n0 >> 3) ^ (row & 7);
        *(uint2*)((char*)A2 + row * 256 + G * 16 + (n0 & 7) * 2) = (uint2){ pk2(v[0], v[1]), pk2(v[2], v[3]) };
    }
    __syncthreads();

    f32x4 acc2[2];
    acc2[0] = (f32x4){0.f,0.f,0.f,0.f}; acc2[1] = (f32x4){0.f,0.f,0.f,0.f};
    #pragma unroll
    for (int kt = 0; kt < 4; kt++) {
        #pragma unroll
        for (int mt = 0; mt < 2; mt++) {
            int row = mt * 16 + row16;
            bf16x8 hf = *(const bf16x8*)((const char*)A2 + row * 256 + (((kt * 4 + kg) ^ (row & 7)) * 16));
            acc2[mt] = __builtin_amdgcn_mfma_f32_16x16x32_bf16(w2[kt], hf, acc2[mt], 0, 0, 0);
        }
    }
    float4 b2v = *(const float4*)(bn2 + n0);
    #pragma unroll
    for (int mt = 0; mt < 2; mt++) {
        int node = nbase + mt * 16 + row16;
        if (node < Nn) {
            float4 ov;
            ov.x = acc2[mt][0] + b2v.x;
            ov.y = acc2[mt][1] + b2v.y;
            ov.z = acc2[mt][2] + b2v.z;
            ov.w = acc2[mt][3] + b2v.w;
            *(float4*)(xout + ((size_t)b * Nn + node) * Hd + n0) = ov;
        }
    }
}

extern "C" void kernel_launch(void* const* d_in, const int* in_sizes, int n_in,
                              void* d_out, int out_size, void* d_ws, size_t ws_size,
                              hipStream_t stream) {
    const float* x   = (const float*)d_in[0];
    const int*   ei  = (const int*)d_in[1];
    const float* ea  = (const float*)d_in[2];
    const float* We1 = (const float*)d_in[3];
    const float* be1 = (const float*)d_in[4];
    const float* We2 = (const float*)d_in[5];
    const float* be2 = (const float*)d_in[6];
    const float* Wn1 = (const float*)d_in[7];
    const float* bn1 = (const float*)d_in[8];
    const float* Wn2 = (const float*)d_in[9];
    const float* bn2 = (const float*)d_in[10];

    float* xout  = (float*)d_out;
    float* e_out = xout + (size_t)Bb * Nn * Hd;     // outputs: x_out, then e

    // ws layout: wbuf | xa | xb | agg(f32) | cnt | cur | part | elist
    char* w = (char*)d_ws;
    short* wbuf  = (short*)w;                               // 229376 B
    short* xa    = (short*)(w + 229376);                    // 25.6 MB
    short* xb    = xa + (size_t)NROWS * Hd;                 // 25.6 MB
    float* agg   = (float*)(xb + (size_t)NROWS * Hd);       // 51.2 MB
    int*   cnt   = (int*)(agg + (size_t)Bb * Nn * Hd);
    int*   cur   = cnt + Nn;
    int*   part  = cur + Nn;                                // 256
    int*   elist = part + 256;                              // Ee

    hipMemsetAsync(cnt, 0, Nn * sizeof(int), stream);
    hipMemsetAsync(agg, 0, (size_t)Bb * Nn * Hd * sizeof(float), stream);

    prep_weights<<<448, 256, 0, stream>>>(We1, We2, Wn1, Wn2, wbuf);
    hist_kernel<<<(Ee + 255) / 256, 256, 0, stream>>>(ei, cnt);
    scan1<<<196, 256, 0, stream>>>(cnt, cur, part);
    scan2<<<1, 64, 0, stream>>>(part);
    scan3<<<196, 256, 0, stream>>>(cur, part);
    scatter_k<<<(Ee + 255) / 256, 256, 0, stream>>>(ei, cur, elist);

    node_pre<<<NROWS / 32, 256, 0, stream>>>(x, wbuf, xa, xb);

    edge_mlp<<<NT2, 512, 0, stream>>>(
        ea, ei, elist, xa, xb, wbuf + 32768, be1, wbuf + 49152, be2, e_out, agg);

    node_mlp<<<Bb * ((Nn + 31) / 32), 512, 0, stream>>>(
        x, agg, wbuf + 65536, bn1, wbuf + 98304, bn2, xout);
}

// Round 13
// 499.452 us; speedup vs baseline: 1.4866x; 1.4866x over previous
//
#include <hip/hip_runtime.h>
#include <hip/hip_bf16.h>

#define Hd 128
#define Nn 50000
#define Ee 400000
#define Bb 2
#define NROWS 100000          // B*N flat node rows
#define TPB2 3125             // 128-edge tiles per batch
#define NT2 6250              // total 128-edge tiles

typedef __attribute__((ext_vector_type(8))) short bf16x8;
typedef __attribute__((ext_vector_type(4))) short bf16x4;
typedef __attribute__((ext_vector_type(4))) float f32x4;

static __device__ __forceinline__ short f2bf(float f) {
    __hip_bfloat16 h = __float2bfloat16(f);
    return *reinterpret_cast<short*>(&h);
}
static __device__ __forceinline__ float bf2f(short s) {
    union { unsigned u; float f; } v; v.u = ((unsigned)(unsigned short)s) << 16;
    return v.f;
}
static __device__ __forceinline__ bf16x8 cvt8(float4 a, float4 b) {
    bf16x8 r;
    r[0] = f2bf(a.x); r[1] = f2bf(a.y); r[2] = f2bf(a.z); r[3] = f2bf(a.w);
    r[4] = f2bf(b.x); r[5] = f2bf(b.y); r[6] = f2bf(b.z); r[7] = f2bf(b.w);
    return r;
}
static __device__ __forceinline__ unsigned pk2(float a, float b) {
    return (unsigned)(unsigned short)f2bf(a) | ((unsigned)(unsigned short)f2bf(b) << 16);
}
// LDS-only barrier: does NOT drain vmcnt.
static __device__ __forceinline__ void lds_barrier() {
    asm volatile("s_waitcnt lgkmcnt(0)" ::: "memory");
    __builtin_amdgcn_s_barrier();
}

// wbuf layout (shorts): WabT[256][128] @0 | W1cT[128][128] @32768 | W2T[128][128] @49152
//                       Wn1T[128][256] @65536 | Wn2T[128][128] @98304   (total 114688)
__global__ void prep_weights(const float* __restrict__ We1, const float* __restrict__ We2,
                             const float* __restrict__ Wn1, const float* __restrict__ Wn2,
                             short* __restrict__ wbuf) {
    int gid = blockIdx.x * 256 + threadIdx.x;
    if (gid < 32768) {
        int c = gid >> 7, k = gid & 127;
        float v = (c < 128) ? We1[k * 128 + c] : We1[(k + 128) * 128 + (c - 128)];
        wbuf[gid] = f2bf(v); return;
    }
    int g = gid - 32768;
    if (g < 16384) { int c = g >> 7, k = g & 127; wbuf[gid] = f2bf(We1[(k + 256) * 128 + c]); return; }
    g -= 16384;
    if (g < 16384) { int c = g >> 7, k = g & 127; wbuf[gid] = f2bf(We2[k * 128 + c]); return; }
    g -= 16384;
    if (g < 32768) { int c = g >> 8, k = g & 255; wbuf[gid] = f2bf(Wn1[k * 128 + c]); return; }
    g -= 32768;
    if (g < 16384) { int c = g >> 7, k = g & 127; wbuf[gid] = f2bf(Wn2[k * 128 + c]); }
}

// ---- CSR by dest (elist = edge ids sorted by dest) ----
__global__ void hist_kernel(const int* __restrict__ ei, int* __restrict__ cnt) {
    int t = blockIdx.x * 256 + threadIdx.x;
    if (t < Ee) atomicAdd(&cnt[ei[Ee + t]], 1);
}
__global__ void scan1(const int* __restrict__ cnt, int* __restrict__ cur, int* __restrict__ part) {
    __shared__ int s[256];
    int i = blockIdx.x * 256 + threadIdx.x;
    int v = (i < Nn) ? cnt[i] : 0;
    s[threadIdx.x] = v; __syncthreads();
    #pragma unroll
    for (int off = 1; off < 256; off <<= 1) {
        int u = (threadIdx.x >= off) ? s[threadIdx.x - off] : 0;
        __syncthreads(); s[threadIdx.x] += u; __syncthreads();
    }
    if (i < Nn) cur[i] = s[threadIdx.x] - v;
    if (threadIdx.x == 255) part[blockIdx.x] = s[255];
}
__global__ void scan2(int* __restrict__ part) {
    if (threadIdx.x == 0 && blockIdx.x == 0) {
        int run = 0;
        for (int i = 0; i < 196; i++) { int t = part[i]; part[i] = run; run += t; }
    }
}
__global__ void scan3(int* __restrict__ cur, const int* __restrict__ part) {
    int i = blockIdx.x * 256 + threadIdx.x;
    if (i < Nn) cur[i] += part[blockIdx.x];
}
__global__ void scatter_k(const int* __restrict__ ei, int* __restrict__ cur, int* __restrict__ elist) {
    int t = blockIdx.x * 256 + threadIdx.x;
    if (t < Ee) { int d = ei[Ee + t]; int pos = atomicAdd(&cur[d], 1); elist[pos] = t; }
}

// ---- node_pre: xa = x@W1a, xb = x@W1b (bf16 out, no bias) ----
__global__ __launch_bounds__(256) void node_pre(
    const float* __restrict__ x, const short* __restrict__ WabT,
    short* __restrict__ xa, short* __restrict__ xb)
{
    __shared__ __align__(16) short X[32 * 128];

    const int nbase = blockIdx.x * 32;
    const int t = threadIdx.x;
    const int wv = t >> 6, lane = t & 63;
    const int row16 = lane & 15, kg = lane >> 4;

    {
        int g = t >> 3, q = t & 7;
        const float* src = x + ((size_t)(nbase + g)) * Hd + q * 16;
        float4 a0 = ((const float4*)src)[0], a1 = ((const float4*)src)[1];
        float4 a2 = ((const float4*)src)[2], a3 = ((const float4*)src)[3];
        ((bf16x8*)X)[g * 16 + ((q * 2) ^ (g & 7))]     = cvt8(a0, a1);
        ((bf16x8*)X)[g * 16 + ((q * 2 + 1) ^ (g & 7))] = cvt8(a2, a3);
    }

    bf16x8 wf[4][4];
    #pragma unroll
    for (int nt = 0; nt < 4; nt++) {
        int n = wv * 64 + nt * 16 + row16;
        #pragma unroll
        for (int kt = 0; kt < 4; kt++)
            wf[kt][nt] = *(const bf16x8*)(WabT + n * 128 + kt * 32 + kg * 8);
    }
    __syncthreads();

    f32x4 acc[2][4];
    #pragma unroll
    for (int mt = 0; mt < 2; mt++)
        #pragma unroll
        for (int nt = 0; nt < 4; nt++) acc[mt][nt] = (f32x4){0.f,0.f,0.f,0.f};

    #pragma unroll
    for (int mt = 0; mt < 2; mt++) {
        int row = mt * 16 + row16;
        #pragma unroll
        for (int kt = 0; kt < 4; kt++) {
            bf16x8 xf = ((const bf16x8*)X)[row * 16 + ((kt * 4 + kg) ^ (row & 7))];
            #pragma unroll
            for (int nt = 0; nt < 4; nt++)
                acc[mt][nt] = __builtin_amdgcn_mfma_f32_16x16x32_bf16(wf[kt][nt], xf, acc[mt][nt], 0, 0, 0);
        }
    }

    #pragma unroll
    for (int mt = 0; mt < 2; mt++) {
        size_t node = nbase + mt * 16 + row16;
        #pragma unroll
        for (int nt = 0; nt < 4; nt++) {
            int ch = wv * 64 + nt * 16 + kg * 4;
            uint2 pk = { pk2(acc[mt][nt][0], acc[mt][nt][1]), pk2(acc[mt][nt][2], acc[mt][nt][3]) };
            short* dst = (ch < 128) ? (xa + node * Hd + ch) : (xb + node * Hd + (ch - 128));
            *(uint2*)dst = pk;
        }
    }
}

// ---- edge_mlp: 128-edge DEST-SORTED tiles, r10 wave structure (8 waves x 16 cols),
//      ONE 32KB LDS region aliased Aea -> A2 -> et(bf16). No VGPR clamp (r12 lesson).
__global__ __launch_bounds__(512) void edge_mlp(
    const float* __restrict__ ea, const int* __restrict__ ei,
    const int* __restrict__ elist,
    const short* __restrict__ xa, const short* __restrict__ xb,
    const short* __restrict__ W1cT, const float* __restrict__ be1,
    const short* __restrict__ W2T, const float* __restrict__ be2,
    float* __restrict__ e_out, float* __restrict__ agg)
{
    __shared__ __align__(16) char smem[32768 + 1536];   // one aliased 32K region + idx
    short* Abuf = (short*)smem;                    // [128 rows][16 groups] — Aea, then A2, then et(bf16)
    int* ol = (int*)(smem + 32768);                // [128]
    int* sl = ol + 128;
    int* dl = sl + 128;

    const int tile = blockIdx.x;
    const int b = tile / TPB2;
    const int w0 = (tile % TPB2) * 128;
    const int t = threadIdx.x;
    const int wv = t >> 6, lane = t & 63;
    const int row16 = lane & 15, kg = lane >> 4;
    const int n0 = wv * 16 + kg * 4;        // this lane's 4 output channels
    const int sr = t >> 3, sq = t & 7;      // staging: row, 64B quarter

    if (t < 128) {
        int o = elist[w0 + t];
        ol[t] = o; sl[t] = ei[o]; dl[t] = ei[Ee + o];
    }
    __syncthreads();

    // per-thread row indices for its 8 MFMA rows
    int on[8], sn[8], dn[8];
    #pragma unroll
    for (int mt = 0; mt < 8; mt++) {
        int r = mt * 16 + row16;
        on[mt] = ol[r]; sn[mt] = sl[r]; dn[mt] = dl[r];
    }

    // stage ea tile: 2 rows per thread (gathered 512B rows, 8 thr x 64B each)
    #pragma unroll
    for (int h = 0; h < 2; h++) {
        int row = sr + h * 64;
        const float* src = ea + ((size_t)b * Ee + ol[row]) * Hd + sq * 16;
        float4 a0 = ((const float4*)src)[0], a1 = ((const float4*)src)[1];
        float4 a2 = ((const float4*)src)[2], a3 = ((const float4*)src)[3];
        ((bf16x8*)Abuf)[row * 16 + ((sq * 2) ^ (row & 7))]     = cvt8(a0, a1);
        ((bf16x8*)Abuf)[row * 16 + ((sq * 2 + 1) ^ (row & 7))] = cvt8(a2, a3);
    }

    bf16x8 w1[4], w2[4];
    {
        const short* wp1 = W1cT + (wv * 16 + row16) * 128 + kg * 8;
        const short* wp2 = W2T  + (wv * 16 + row16) * 128 + kg * 8;
        #pragma unroll
        for (int kt = 0; kt < 4; kt++) {
            w1[kt] = *(const bf16x8*)(wp1 + kt * 32);
            w2[kt] = *(const bf16x8*)(wp2 + kt * 32);
        }
    }
    // xa/xb gathers (xb dest-sorted -> cache-hot); issued early, consumed in epilogue
    bf16x4 av[8], bv[8];
    #pragma unroll
    for (int mt = 0; mt < 8; mt++) {
        av[mt] = *(const bf16x4*)(xa + ((size_t)b * Nn + sn[mt]) * Hd + n0);
        bv[mt] = *(const bf16x4*)(xb + ((size_t)b * Nn + dn[mt]) * Hd + n0);
    }
    const float4 b1v = *(const float4*)(be1 + n0);
    const float4 b2v = *(const float4*)(be2 + n0);
    lds_barrier();

    // L1 GEMM: 32 MFMA (reads Aea)
    f32x4 acc[8];
    #pragma unroll
    for (int mt = 0; mt < 8; mt++) acc[mt] = (f32x4){0.f,0.f,0.f,0.f};
    #pragma unroll
    for (int kt = 0; kt < 4; kt++) {
        #pragma unroll
        for (int mt = 0; mt < 8; mt++) {
            int row = mt * 16 + row16;
            bf16x8 af = ((const bf16x8*)Abuf)[row * 16 + ((kt * 4 + kg) ^ (row & 7))];
            acc[mt] = __builtin_amdgcn_mfma_f32_16x16x32_bf16(w1[kt], af, acc[mt], 0, 0, 0);
        }
    }
    lds_barrier();   // all Aea reads complete -> region may be rewritten as A2

    // epilogue: bias + skip adds + relu -> A2 (bf16 swizzled, same region)
    #pragma unroll
    for (int mt = 0; mt < 8; mt++) {
        int row = mt * 16 + row16;
        float vv[4];
        #pragma unroll
        for (int r = 0; r < 4; r++) {
            float u = acc[mt][r] + b1v[r] + bf2f(av[mt][r]) + bf2f(bv[mt][r]);
            vv[r] = u > 0.f ? u : 0.f;
        }
        int G = (n0 >> 3) ^ (row & 7);
        *(uint2*)((char*)Abuf + row * 256 + G * 16 + (n0 & 7) * 2) =
            (uint2){ pk2(vv[0], vv[1]), pk2(vv[2], vv[3]) };
    }
    lds_barrier();

    // L2 GEMM: 32 MFMA (reads A2)
    f32x4 acc2[8];
    #pragma unroll
    for (int mt = 0; mt < 8; mt++) acc2[mt] = (f32x4){0.f,0.f,0.f,0.f};
    #pragma unroll
    for (int kt = 0; kt < 4; kt++) {
        #pragma unroll
        for (int mt = 0; mt < 8; mt++) {
            int row = mt * 16 + row16;
            bf16x8 hf = *(const bf16x8*)((const char*)Abuf + row * 256 + (((kt * 4 + kg) ^ (row & 7)) * 16));
            acc2[mt] = __builtin_amdgcn_mfma_f32_16x16x32_bf16(w2[kt], hf, acc2[mt], 0, 0, 0);
        }
    }

    // finalize e = acc2 + b2; store to e_out (scattered 16B, fire-and-forget)
    #pragma unroll
    for (int mt = 0; mt < 8; mt++) {
        acc2[mt][0] += b2v.x; acc2[mt][1] += b2v.y;
        acc2[mt][2] += b2v.z; acc2[mt][3] += b2v.w;
        float4 ov = { acc2[mt][0], acc2[mt][1], acc2[mt][2], acc2[mt][3] };
        *(float4*)(e_out + ((size_t)b * Ee + on[mt]) * Hd + n0) = ov;
    }
    lds_barrier();   // all A2 reads complete -> region may be rewritten as et

    // restage e-tile as bf16 into et[128][128] (16B-group swizzle), same region
    #pragma unroll
    for (int mt = 0; mt < 8; mt++) {
        int row = mt * 16 + row16;
        int G = (n0 >> 3) ^ (row & 7);
        *(uint2*)((char*)Abuf + row * 256 + G * 16 + (n0 & 7) * 2) =
            (uint2){ pk2(acc2[mt][0], acc2[mt][1]), pk2(acc2[mt][2], acc2[mt][3]) };
    }
    lds_barrier();

    // segment-sum over sorted dests -> few atomics. thread owns channel c, 32-row group.
    {
        int c = t & 127, rg2 = t >> 7;
        int gc = c >> 3, sub = (c & 7) * 2;
        int base = rg2 * 32;
        float s = 0.f;
        int pd = dl[base];
        #pragma unroll
        for (int i = 0; i < 32; i++) {
            int row = base + i;
            float v = bf2f(*(const short*)((const char*)Abuf + row * 256 + ((gc ^ (row & 7)) << 4) + sub));
            int d = dl[row];
            if (d != pd) {
                unsafeAtomicAdd(agg + ((size_t)b * Nn + pd) * Hd + c, s);
                s = 0.f; pd = d;
            }
            s += v;
        }
        unsafeAtomicAdd(agg + ((size_t)b * Nn + pd) * Hd + c, s);
    }
}

// ---- node_mlp (streaming): x_out = relu(concat(x, agg) @ Wn1 + bn1) @ Wn2 + bn2 ----
__global__ __launch_bounds__(512, 4) void node_mlp(
    const float* __restrict__ x, const float* __restrict__ agg,
    const short* __restrict__ Wn1T, const float* __restrict__ bn1,
    const short* __restrict__ Wn2T, const float* __restrict__ bn2,
    float* __restrict__ xout)
{
    __shared__ __align__(16) short A[32 * 256];      // 16KB: [node][32 groups] (x | agg)
    __shared__ __align__(16) short A2[32 * 128];     // 8KB hidden

    const int tilesPerB = (Nn + 31) / 32;            // 1563
    const int bid = blockIdx.x;
    const int b = bid / tilesPerB;
    const int nbase = (bid % tilesPerB) * 32;
    const int t = threadIdx.x;
    const int wv = t >> 6, lane = t & 63;
    const int row16 = lane & 15, kg = lane >> 4;
    const int n0 = wv * 16 + kg * 4;

    {
        int g = t >> 4, q2 = t & 15;
        int n = nbase + g;
        float4 xv0 = {0,0,0,0}, xv1 = xv0;
        float4 s0 = {0,0,0,0}, s1 = s0;
        if (n < Nn) {
            const float* xr = x + ((size_t)b * Nn + n) * Hd + q2 * 8;
            xv0 = ((const float4*)xr)[0]; xv1 = ((const float4*)xr)[1];
            const float* ar = agg + ((size_t)b * Nn + n) * Hd + q2 * 8;
            s0 = ((const float4*)ar)[0]; s1 = ((const float4*)ar)[1];
        }
        ((bf16x8*)A)[g * 32 + (q2 ^ (g & 7))]        = cvt8(xv0, xv1);
        ((bf16x8*)A)[g * 32 + ((16 + q2) ^ (g & 7))] = cvt8(s0, s1);
    }

    bf16x8 w1[8];
    {
        const short* wp = Wn1T + (wv * 16 + row16) * 256 + kg * 8;
        #pragma unroll
        for (int kt = 0; kt < 8; kt++) w1[kt] = *(const bf16x8*)(wp + kt * 32);
    }
    __syncthreads();

    f32x4 acc[2];
    acc[0] = (f32x4){0.f,0.f,0.f,0.f}; acc[1] = (f32x4){0.f,0.f,0.f,0.f};
    #pragma unroll
    for (int kt = 0; kt < 8; kt++) {
        #pragma unroll
        for (int mt = 0; mt < 2; mt++) {
            int row = mt * 16 + row16;
            bf16x8 af = ((const bf16x8*)A)[row * 32 + ((kt * 4 + kg) ^ (row & 7))];
            acc[mt] = __builtin_amdgcn_mfma_f32_16x16x32_bf16(w1[kt], af, acc[mt], 0, 0, 0);
        }
    }

    float4 b1v = *(const float4*)(bn1 + n0);
    bf16x8 w2[4];
    {
        const short* wp = Wn2T + (wv * 16 + row16) * 128 + kg * 8;
        #pragma unroll
        for (int kt = 0; kt < 4; kt++) w2[kt] = *(const bf16x8*)(wp + kt * 32);
    }

    #pragma unroll
    for (int mt = 0; mt < 2; mt++) {
        int row = mt * 16 + row16;
        float v[4];
        #pragma unroll
        for (int r = 0; r < 4; r++) {
            float u = acc[mt][r] + b1v[r];
            v[r] = u > 0.f ? u : 0.f;
        }
        int G = (n0 >> 3) ^ (row & 7);
        *(uint2*)((char*)A2 + row * 256 + G * 16 + (n0 & 7) * 2) = (uint2){ pk2(v[0], v[1]), pk2(v[2], v[3]) };
    }
    __syncthreads();

    f32x4 acc2[2];
    acc2[0] = (f32x4){0.f,0.f,0.f,0.f}; acc2[1] = (f32x4){0.f,0.f,0.f,0.f};
    #pragma unroll
    for (int kt = 0; kt < 4; kt++) {
        #pragma unroll
        for (int mt = 0; mt < 2; mt++) {
            int row = mt * 16 + row16;
            bf16x8 hf = *(const bf16x8*)((const char*)A2 + row * 256 + (((kt * 4 + kg) ^ (row & 7)) * 16));
            acc2[mt] = __builtin_amdgcn_mfma_f32_16x16x32_bf16(w2[kt], hf, acc2[mt], 0, 0, 0);
        }
    }
    float4 b2v = *(const float4*)(bn2 + n0);
    #pragma unroll
    for (int mt = 0; mt < 2; mt++) {
        int node = nbase + mt * 16 + row16;
        if (node < Nn) {
            float4 ov;
            ov.x = acc2[mt][0] + b2v.x;
            ov.y = acc2[mt][1] + b2v.y;
            ov.z = acc2[mt][2] + b2v.z;
            ov.w = acc2[mt][3] + b2v.w;
            *(float4*)(xout + ((size_t)b * Nn + node) * Hd + n0) = ov;
        }
    }
}

extern "C" void kernel_launch(void* const* d_in, const int* in_sizes, int n_in,
                              void* d_out, int out_size, void* d_ws, size_t ws_size,
                              hipStream_t stream) {
    const float* x   = (const float*)d_in[0];
    const int*   ei  = (const int*)d_in[1];
    const float* ea  = (const float*)d_in[2];
    const float* We1 = (const float*)d_in[3];
    const float* be1 = (const float*)d_in[4];
    const float* We2 = (const float*)d_in[5];
    const float* be2 = (const float*)d_in[6];
    const float* Wn1 = (const float*)d_in[7];
    const float* bn1 = (const float*)d_in[8];
    const float* Wn2 = (const float*)d_in[9];
    const float* bn2 = (const float*)d_in[10];

    float* xout  = (float*)d_out;
    float* e_out = xout + (size_t)Bb * Nn * Hd;     // outputs: x_out, then e

    // ws layout: wbuf | xa | xb | agg(f32) | cnt | cur | part | elist
    char* w = (char*)d_ws;
    short* wbuf  = (short*)w;                               // 229376 B
    short* xa    = (short*)(w + 229376);                    // 25.6 MB
    short* xb    = xa + (size_t)NROWS * Hd;                 // 25.6 MB
    float* agg   = (float*)(xb + (size_t)NROWS * Hd);       // 51.2 MB
    int*   cnt   = (int*)(agg + (size_t)Bb * Nn * Hd);
    int*   cur   = cnt + Nn;
    int*   part  = cur + Nn;                                // 256
    int*   elist = part + 256;                              // Ee

    hipMemsetAsync(cnt, 0, Nn * sizeof(int), stream);
    hipMemsetAsync(agg, 0, (size_t)Bb * Nn * Hd * sizeof(float), stream);

    prep_weights<<<448, 256, 0, stream>>>(We1, We2, Wn1, Wn2, wbuf);
    hist_kernel<<<(Ee + 255) / 256, 256, 0, stream>>>(ei, cnt);
    scan1<<<196, 256, 0, stream>>>(cnt, cur, part);
    scan2<<<1, 64, 0, stream>>>(part);
    scan3<<<196, 256, 0, stream>>>(cur, part);
    scatter_k<<<(Ee + 255) / 256, 256, 0, stream>>>(ei, cur, elist);

    node_pre<<<NROWS / 32, 256, 0, stream>>>(x, wbuf, xa, xb);

    edge_mlp<<<NT2, 512, 0, stream>>>(
        ea, ei, elist, xa, xb, wbuf + 32768, be1, wbuf + 49152, be2, e_out, agg);

    node_mlp<<<Bb * ((Nn + 31) / 32), 512, 0, stream>>>(
        x, agg, wbuf + 65536, bn1, wbuf + 98304, bn2, xout);
}

// Round 14
// 453.783 us; speedup vs baseline: 1.6362x; 1.1006x over previous
//
#include <hip/hip_runtime.h>
#include <hip/hip_bf16.h>

#define Hd 128
#define Nn 50000
#define Ee 400000
#define Bb 2
#define NROWS 100000          // B*N flat node rows
#define TPB2 3125             // 128-edge tiles per batch
#define NT2 6250              // total 128-edge tiles

typedef __attribute__((ext_vector_type(8))) short bf16x8;
typedef __attribute__((ext_vector_type(4))) short bf16x4;
typedef __attribute__((ext_vector_type(4))) float f32x4;

static __device__ __forceinline__ short f2bf(float f) {
    __hip_bfloat16 h = __float2bfloat16(f);
    return *reinterpret_cast<short*>(&h);
}
static __device__ __forceinline__ float bf2f(short s) {
    union { unsigned u; float f; } v; v.u = ((unsigned)(unsigned short)s) << 16;
    return v.f;
}
static __device__ __forceinline__ bf16x8 cvt8(float4 a, float4 b) {
    bf16x8 r;
    r[0] = f2bf(a.x); r[1] = f2bf(a.y); r[2] = f2bf(a.z); r[3] = f2bf(a.w);
    r[4] = f2bf(b.x); r[5] = f2bf(b.y); r[6] = f2bf(b.z); r[7] = f2bf(b.w);
    return r;
}
static __device__ __forceinline__ unsigned pk2(float a, float b) {
    return (unsigned)(unsigned short)f2bf(a) | ((unsigned)(unsigned short)f2bf(b) << 16);
}
// LDS-only barrier: does NOT drain vmcnt.
static __device__ __forceinline__ void lds_barrier() {
    asm volatile("s_waitcnt lgkmcnt(0)" ::: "memory");
    __builtin_amdgcn_s_barrier();
}

// wbuf layout (shorts): WabT[256][128] @0 | W1cT[128][128] @32768 | W2T[128][128] @49152
//                       Wn1T[128][256] @65536 | Wn2T[128][128] @98304   (total 114688)
__global__ void prep_weights(const float* __restrict__ We1, const float* __restrict__ We2,
                             const float* __restrict__ Wn1, const float* __restrict__ Wn2,
                             short* __restrict__ wbuf) {
    int gid = blockIdx.x * 256 + threadIdx.x;
    if (gid < 32768) {
        int c = gid >> 7, k = gid & 127;
        float v = (c < 128) ? We1[k * 128 + c] : We1[(k + 128) * 128 + (c - 128)];
        wbuf[gid] = f2bf(v); return;
    }
    int g = gid - 32768;
    if (g < 16384) { int c = g >> 7, k = g & 127; wbuf[gid] = f2bf(We1[(k + 256) * 128 + c]); return; }
    g -= 16384;
    if (g < 16384) { int c = g >> 7, k = g & 127; wbuf[gid] = f2bf(We2[k * 128 + c]); return; }
    g -= 16384;
    if (g < 32768) { int c = g >> 8, k = g & 255; wbuf[gid] = f2bf(Wn1[k * 128 + c]); return; }
    g -= 32768;
    if (g < 16384) { int c = g >> 7, k = g & 127; wbuf[gid] = f2bf(Wn2[k * 128 + c]); }
}

// ---- CSR by dest (elist = edge ids sorted by dest) ----
__global__ void hist_kernel(const int* __restrict__ ei, int* __restrict__ cnt) {
    int t = blockIdx.x * 256 + threadIdx.x;
    if (t < Ee) atomicAdd(&cnt[ei[Ee + t]], 1);
}
__global__ void scan1(const int* __restrict__ cnt, int* __restrict__ cur, int* __restrict__ part) {
    __shared__ int s[256];
    int i = blockIdx.x * 256 + threadIdx.x;
    int v = (i < Nn) ? cnt[i] : 0;
    s[threadIdx.x] = v; __syncthreads();
    #pragma unroll
    for (int off = 1; off < 256; off <<= 1) {
        int u = (threadIdx.x >= off) ? s[threadIdx.x - off] : 0;
        __syncthreads(); s[threadIdx.x] += u; __syncthreads();
    }
    if (i < Nn) cur[i] = s[threadIdx.x] - v;
    if (threadIdx.x == 255) part[blockIdx.x] = s[255];
}
__global__ void scan2(int* __restrict__ part) {
    if (threadIdx.x == 0 && blockIdx.x == 0) {
        int run = 0;
        for (int i = 0; i < 196; i++) { int t = part[i]; part[i] = run; run += t; }
    }
}
__global__ void scan3(int* __restrict__ cur, const int* __restrict__ part) {
    int i = blockIdx.x * 256 + threadIdx.x;
    if (i < Nn) cur[i] += part[blockIdx.x];
}
__global__ void scatter_k(const int* __restrict__ ei, int* __restrict__ cur, int* __restrict__ elist) {
    int t = blockIdx.x * 256 + threadIdx.x;
    if (t < Ee) { int d = ei[Ee + t]; int pos = atomicAdd(&cur[d], 1); elist[pos] = t; }
}

// ---- node_pre: xa = x@W1a, xb = x@W1b (bf16 out, no bias) ----
__global__ __launch_bounds__(256) void node_pre(
    const float* __restrict__ x, const short* __restrict__ WabT,
    short* __restrict__ xa, short* __restrict__ xb)
{
    __shared__ __align__(16) short X[32 * 128];

    const int nbase = blockIdx.x * 32;
    const int t = threadIdx.x;
    const int wv = t >> 6, lane = t & 63;
    const int row16 = lane & 15, kg = lane >> 4;

    {
        int g = t >> 3, q = t & 7;
        const float* src = x + ((size_t)(nbase + g)) * Hd + q * 16;
        float4 a0 = ((const float4*)src)[0], a1 = ((const float4*)src)[1];
        float4 a2 = ((const float4*)src)[2], a3 = ((const float4*)src)[3];
        ((bf16x8*)X)[g * 16 + ((q * 2) ^ (g & 7))]     = cvt8(a0, a1);
        ((bf16x8*)X)[g * 16 + ((q * 2 + 1) ^ (g & 7))] = cvt8(a2, a3);
    }

    bf16x8 wf[4][4];
    #pragma unroll
    for (int nt = 0; nt < 4; nt++) {
        int n = wv * 64 + nt * 16 + row16;
        #pragma unroll
        for (int kt = 0; kt < 4; kt++)
            wf[kt][nt] = *(const bf16x8*)(WabT + n * 128 + kt * 32 + kg * 8);
    }
    __syncthreads();

    f32x4 acc[2][4];
    #pragma unroll
    for (int mt = 0; mt < 2; mt++)
        #pragma unroll
        for (int nt = 0; nt < 4; nt++) acc[mt][nt] = (f32x4){0.f,0.f,0.f,0.f};

    #pragma unroll
    for (int mt = 0; mt < 2; mt++) {
        int row = mt * 16 + row16;
        #pragma unroll
        for (int kt = 0; kt < 4; kt++) {
            bf16x8 xf = ((const bf16x8*)X)[row * 16 + ((kt * 4 + kg) ^ (row & 7))];
            #pragma unroll
            for (int nt = 0; nt < 4; nt++)
                acc[mt][nt] = __builtin_amdgcn_mfma_f32_16x16x32_bf16(wf[kt][nt], xf, acc[mt][nt], 0, 0, 0);
        }
    }

    #pragma unroll
    for (int mt = 0; mt < 2; mt++) {
        size_t node = nbase + mt * 16 + row16;
        #pragma unroll
        for (int nt = 0; nt < 4; nt++) {
            int ch = wv * 64 + nt * 16 + kg * 4;
            uint2 pk = { pk2(acc[mt][nt][0], acc[mt][nt][1]), pk2(acc[mt][nt][2], acc[mt][nt][3]) };
            short* dst = (ch < 128) ? (xa + node * Hd + ch) : (xb + node * Hd + (ch - 128));
            *(uint2*)dst = pk;
        }
    }
}

// ---- edge_mlp: 128-edge DEST-SORTED tiles (r10 structure), XCD-chunked tile swizzle,
//      shared accumulator array for L1/L2, fused segment-sum -> agg ----
__global__ __launch_bounds__(512) void edge_mlp(
    const float* __restrict__ ea, const int* __restrict__ ei,
    const int* __restrict__ elist,
    const short* __restrict__ xa, const short* __restrict__ xb,
    const short* __restrict__ W1cT, const float* __restrict__ be1,
    const short* __restrict__ W2T, const float* __restrict__ be2,
    float* __restrict__ e_out, float* __restrict__ agg)
{
    // smem: Aea[32K bf16] | A2[32K bf16]; after both GEMMs the 64K is reused as et[128][512B] f32
    __shared__ __align__(16) char smem[65536 + 1536];
    short* Aea = (short*)smem;                     // [128 rows][16 groups]
    short* A2  = (short*)(smem + 32768);           // [128 rows][16 groups]
    int* ol = (int*)(smem + 65536);                // [128]
    int* sl = ol + 128;
    int* dl = sl + 128;

    // XCD-chunked bijective swizzle: blocks resident on one XCD process contiguous
    // dest-sorted tile ranges -> xb gathers + agg atomics become L2-local. [T1, m204]
    const int orig = blockIdx.x;
    const int q = NT2 / 8, rr = NT2 % 8;           // 781, 2
    const int xcd = orig & 7, idx = orig >> 3;
    const int tile = (xcd < rr ? xcd * (q + 1) : rr * (q + 1) + (xcd - rr) * q) + idx;

    const int b = tile / TPB2;
    const int w0 = (tile % TPB2) * 128;
    const int t = threadIdx.x;
    const int wv = t >> 6, lane = t & 63;
    const int row16 = lane & 15, kg = lane >> 4;
    const int n0 = wv * 16 + kg * 4;        // this lane's 4 output channels
    const int sr = t >> 3, sq = t & 7;      // staging: row, 64B quarter

    if (t < 128) {
        int o = elist[w0 + t];
        ol[t] = o; sl[t] = ei[o]; dl[t] = ei[Ee + o];
    }
    __syncthreads();

    // per-thread row indices for its 8 MFMA rows
    int on[8], sn[8], dn[8];
    #pragma unroll
    for (int mt = 0; mt < 8; mt++) {
        int r = mt * 16 + row16;
        on[mt] = ol[r]; sn[mt] = sl[r]; dn[mt] = dl[r];
    }

    // stage ea tile: 2 rows per thread (gathered 512B rows, 8 thr x 64B each)
    #pragma unroll
    for (int h = 0; h < 2; h++) {
        int row = sr + h * 64;
        const float* src = ea + ((size_t)b * Ee + ol[row]) * Hd + sq * 16;
        float4 a0 = ((const float4*)src)[0], a1 = ((const float4*)src)[1];
        float4 a2 = ((const float4*)src)[2], a3 = ((const float4*)src)[3];
        ((bf16x8*)Aea)[row * 16 + ((sq * 2) ^ (row & 7))]     = cvt8(a0, a1);
        ((bf16x8*)Aea)[row * 16 + ((sq * 2 + 1) ^ (row & 7))] = cvt8(a2, a3);
    }

    bf16x8 w1[4], w2[4];
    {
        const short* wp1 = W1cT + (wv * 16 + row16) * 128 + kg * 8;
        const short* wp2 = W2T  + (wv * 16 + row16) * 128 + kg * 8;
        #pragma unroll
        for (int kt = 0; kt < 4; kt++) {
            w1[kt] = *(const bf16x8*)(wp1 + kt * 32);
            w2[kt] = *(const bf16x8*)(wp2 + kt * 32);
        }
    }
    // xa/xb gathers (xb dest-sorted + XCD-chunked -> L2-hot); issued early
    bf16x4 av[8], bv[8];
    #pragma unroll
    for (int mt = 0; mt < 8; mt++) {
        av[mt] = *(const bf16x4*)(xa + ((size_t)b * Nn + sn[mt]) * Hd + n0);
        bv[mt] = *(const bf16x4*)(xb + ((size_t)b * Nn + dn[mt]) * Hd + n0);
    }
    const float4 b1v = *(const float4*)(be1 + n0);
    const float4 b2v = *(const float4*)(be2 + n0);
    lds_barrier();

    // L1 GEMM: 32 MFMA (reads Aea)
    f32x4 acc[8];
    #pragma unroll
    for (int mt = 0; mt < 8; mt++) acc[mt] = (f32x4){0.f,0.f,0.f,0.f};
    #pragma unroll
    for (int kt = 0; kt < 4; kt++) {
        #pragma unroll
        for (int mt = 0; mt < 8; mt++) {
            int row = mt * 16 + row16;
            bf16x8 af = ((const bf16x8*)Aea)[row * 16 + ((kt * 4 + kg) ^ (row & 7))];
            acc[mt] = __builtin_amdgcn_mfma_f32_16x16x32_bf16(w1[kt], af, acc[mt], 0, 0, 0);
        }
    }

    // epilogue: bias + skip adds + relu -> A2 (bf16 swizzled; separate region, no barrier needed)
    #pragma unroll
    for (int mt = 0; mt < 8; mt++) {
        int row = mt * 16 + row16;
        float vv[4];
        #pragma unroll
        for (int r = 0; r < 4; r++) {
            float u = acc[mt][r] + b1v[r] + bf2f(av[mt][r]) + bf2f(bv[mt][r]);
            vv[r] = u > 0.f ? u : 0.f;
        }
        int G = (n0 >> 3) ^ (row & 7);
        *(uint2*)((char*)A2 + row * 256 + G * 16 + (n0 & 7) * 2) =
            (uint2){ pk2(vv[0], vv[1]), pk2(vv[2], vv[3]) };
    }
    lds_barrier();

    // L2 GEMM: 32 MFMA (reads A2) — REUSE acc registers (disjoint lifetime; r13 lesson: force AGPR sharing)
    #pragma unroll
    for (int mt = 0; mt < 8; mt++) acc[mt] = (f32x4){0.f,0.f,0.f,0.f};
    #pragma unroll
    for (int kt = 0; kt < 4; kt++) {
        #pragma unroll
        for (int mt = 0; mt < 8; mt++) {
            int row = mt * 16 + row16;
            bf16x8 hf = *(const bf16x8*)((const char*)A2 + row * 256 + (((kt * 4 + kg) ^ (row & 7)) * 16));
            acc[mt] = __builtin_amdgcn_mfma_f32_16x16x32_bf16(w2[kt], hf, acc[mt], 0, 0, 0);
        }
    }

    // finalize e = acc + b2; store to e_out (scattered 16B, fire-and-forget)
    #pragma unroll
    for (int mt = 0; mt < 8; mt++) {
        acc[mt][0] += b2v.x; acc[mt][1] += b2v.y;
        acc[mt][2] += b2v.z; acc[mt][3] += b2v.w;
        float4 ov = { acc[mt][0], acc[mt][1], acc[mt][2], acc[mt][3] };
        *(float4*)(e_out + ((size_t)b * Ee + on[mt]) * Hd + n0) = ov;
    }
    lds_barrier();   // all Aea/A2 reads done -> whole 64K may be rewritten as et

    // restage e-tile f32 into et[128][512B] (16B-group swizzle: g' = g ^ (row&7))
    #pragma unroll
    for (int mt = 0; mt < 8; mt++) {
        int row = mt * 16 + row16;
        float4 ov = { acc[mt][0], acc[mt][1], acc[mt][2], acc[mt][3] };
        *(float4*)(smem + row * 512 + (((n0 >> 2) ^ (row & 7)) << 4)) = ov;
    }
    lds_barrier();

    // segment-sum over sorted dests -> few atomics. thread owns channel c, 32-row group.
    {
        int c = t & 127, rg2 = t >> 7;
        int g_c = c >> 2, sub = (c & 3) << 2;
        int base = rg2 * 32;
        float s = 0.f;
        int pd = dl[base];
        #pragma unroll
        for (int i = 0; i < 32; i++) {
            int row = base + i;
            float v = *(const float*)(smem + row * 512 + ((g_c ^ (row & 7)) << 4) + sub);
            int d = dl[row];
            if (d != pd) {
                unsafeAtomicAdd(agg + ((size_t)b * Nn + pd) * Hd + c, s);
                s = 0.f; pd = d;
            }
            s += v;
        }
        unsafeAtomicAdd(agg + ((size_t)b * Nn + pd) * Hd + c, s);
    }
}

// ---- node_mlp (streaming): x_out = relu(concat(x, agg) @ Wn1 + bn1) @ Wn2 + bn2 ----
__global__ __launch_bounds__(512, 4) void node_mlp(
    const float* __restrict__ x, const float* __restrict__ agg,
    const short* __restrict__ Wn1T, const float* __restrict__ bn1,
    const short* __restrict__ Wn2T, const float* __restrict__ bn2,
    float* __restrict__ xout)
{
    __shared__ __align__(16) short A[32 * 256];      // 16KB: [node][32 groups] (x | agg)
    __shared__ __align__(16) short A2[32 * 128];     // 8KB hidden

    const int tilesPerB = (Nn + 31) / 32;            // 1563
    const int bid = blockIdx.x;
    const int b = bid / tilesPerB;
    const int nbase = (bid % tilesPerB) * 32;
    const int t = threadIdx.x;
    const int wv = t >> 6, lane = t & 63;
    const int row16 = lane & 15, kg = lane >> 4;
    const int n0 = wv * 16 + kg * 4;

    {
        int g = t >> 4, q2 = t & 15;
        int n = nbase + g;
        float4 xv0 = {0,0,0,0}, xv1 = xv0;
        float4 s0 = {0,0,0,0}, s1 = s0;
        if (n < Nn) {
            const float* xr = x + ((size_t)b * Nn + n) * Hd + q2 * 8;
            xv0 = ((const float4*)xr)[0]; xv1 = ((const float4*)xr)[1];
            const float* ar = agg + ((size_t)b * Nn + n) * Hd + q2 * 8;
            s0 = ((const float4*)ar)[0]; s1 = ((const float4*)ar)[1];
        }
        ((bf16x8*)A)[g * 32 + (q2 ^ (g & 7))]        = cvt8(xv0, xv1);
        ((bf16x8*)A)[g * 32 + ((16 + q2) ^ (g & 7))] = cvt8(s0, s1);
    }

    bf16x8 w1[8];
    {
        const short* wp = Wn1T + (wv * 16 + row16) * 256 + kg * 8;
        #pragma unroll
        for (int kt = 0; kt < 8; kt++) w1[kt] = *(const bf16x8*)(wp + kt * 32);
    }
    __syncthreads();

    f32x4 acc[2];
    acc[0] = (f32x4){0.f,0.f,0.f,0.f}; acc[1] = (f32x4){0.f,0.f,0.f,0.f};
    #pragma unroll
    for (int kt = 0; kt < 8; kt++) {
        #pragma unroll
        for (int mt = 0; mt < 2; mt++) {
            int row = mt * 16 + row16;
            bf16x8 af = ((const bf16x8*)A)[row * 32 + ((kt * 4 + kg) ^ (row & 7))];
            acc[mt] = __builtin_amdgcn_mfma_f32_16x16x32_bf16(w1[kt], af, acc[mt], 0, 0, 0);
        }
    }

    float4 b1v = *(const float4*)(bn1 + n0);
    bf16x8 w2[4];
    {
        const short* wp = Wn2T + (wv * 16 + row16) * 128 + kg * 8;
        #pragma unroll
        for (int kt = 0; kt < 4; kt++) w2[kt] = *(const bf16x8*)(wp + kt * 32);
    }

    #pragma unroll
    for (int mt = 0; mt < 2; mt++) {
        int row = mt * 16 + row16;
        float v[4];
        #pragma unroll
        for (int r = 0; r < 4; r++) {
            float u = acc[mt][r] + b1v[r];
            v[r] = u > 0.f ? u : 0.f;
        }
        int G = (n0 >> 3) ^ (row & 7);
        *(uint2*)((char*)A2 + row * 256 + G * 16 + (n0 & 7) * 2) = (uint2){ pk2(v[0], v[1]), pk2(v[2], v[3]) };
    }
    __syncthreads();

    f32x4 acc2[2];
    acc2[0] = (f32x4){0.f,0.f,0.f,0.f}; acc2[1] = (f32x4){0.f,0.f,0.f,0.f};
    #pragma unroll
    for (int kt = 0; kt < 4; kt++) {
        #pragma unroll
        for (int mt = 0; mt < 2; mt++) {
            int row = mt * 16 + row16;
            bf16x8 hf = *(const bf16x8*)((const char*)A2 + row * 256 + (((kt * 4 + kg) ^ (row & 7)) * 16));
            acc2[mt] = __builtin_amdgcn_mfma_f32_16x16x32_bf16(w2[kt], hf, acc2[mt], 0, 0, 0);
        }
    }
    float4 b2v = *(const float4*)(bn2 + n0);
    #pragma unroll
    for (int mt = 0; mt < 2; mt++) {
        int node = nbase + mt * 16 + row16;
        if (node < Nn) {
            float4 ov;
            ov.x = acc2[mt][0] + b2v.x;
            ov.y = acc2[mt][1] + b2v.y;
            ov.z = acc2[mt][2] + b2v.z;
            ov.w = acc2[mt][3] + b2v.w;
            *(float4*)(xout + ((size_t)b * Nn + node) * Hd + n0) = ov;
        }
    }
}

extern "C" void kernel_launch(void* const* d_in, const int* in_sizes, int n_in,
                              void* d_out, int out_size, void* d_ws, size_t ws_size,
                              hipStream_t stream) {
    const float* x   = (const float*)d_in[0];
    const int*   ei  = (const int*)d_in[1];
    const float* ea  = (const float*)d_in[2];
    const float* We1 = (const float*)d_in[3];
    const float* be1 = (const float*)d_in[4];
    const float* We2 = (const float*)d_in[5];
    const float* be2 = (const float*)d_in[6];
    const float* Wn1 = (const float*)d_in[7];
    const float* bn1 = (const float*)d_in[8];
    const float* Wn2 = (const float*)d_in[9];
    const float* bn2 = (const float*)d_in[10];

    float* xout  = (float*)d_out;
    float* e_out = xout + (size_t)Bb * Nn * Hd;     // outputs: x_out, then e

    // ws layout: wbuf | xa | xb | agg(f32) | cnt | cur | part | elist
    char* w = (char*)d_ws;
    short* wbuf  = (short*)w;                               // 229376 B
    short* xa    = (short*)(w + 229376);                    // 25.6 MB
    short* xb    = xa + (size_t)NROWS * Hd;                 // 25.6 MB
    float* agg   = (float*)(xb + (size_t)NROWS * Hd);       // 51.2 MB
    int*   cnt   = (int*)(agg + (size_t)Bb * Nn * Hd);
    int*   cur   = cnt + Nn;
    int*   part  = cur + Nn;                                // 256
    int*   elist = part + 256;                              // Ee

    hipMemsetAsync(cnt, 0, Nn * sizeof(int), stream);
    hipMemsetAsync(agg, 0, (size_t)Bb * Nn * Hd * sizeof(float), stream);

    prep_weights<<<448, 256, 0, stream>>>(We1, We2, Wn1, Wn2, wbuf);
    hist_kernel<<<(Ee + 255) / 256, 256, 0, stream>>>(ei, cnt);
    scan1<<<196, 256, 0, stream>>>(cnt, cur, part);
    scan2<<<1, 64, 0, stream>>>(part);
    scan3<<<196, 256, 0, stream>>>(cur, part);
    scatter_k<<<(Ee + 255) / 256, 256, 0, stream>>>(ei, cur, elist);

    node_pre<<<NROWS / 32, 256, 0, stream>>>(x, wbuf, xa, xb);

    edge_mlp<<<NT2, 512, 0, stream>>>(
        ea, ei, elist, xa, xb, wbuf + 32768, be1, wbuf + 49152, be2, e_out, agg);

    node_mlp<<<Bb * ((Nn + 31) / 32), 512, 0, stream>>>(
        x, agg, wbuf + 65536, bn1, wbuf + 98304, bn2, xout);
}

// Round 15
// 436.671 us; speedup vs baseline: 1.7003x; 1.0392x over previous
//
#include <hip/hip_runtime.h>
#include <hip/hip_bf16.h>

#define Hd 128
#define Nn 50000
#define Ee 400000
#define Bb 2
#define NROWS 100000          // B*N flat node rows
#define TPB2 3125             // 128-edge tiles per batch
#define NT2 6250              // total 128-edge tiles

typedef __attribute__((ext_vector_type(8))) short bf16x8;
typedef __attribute__((ext_vector_type(4))) short bf16x4;
typedef __attribute__((ext_vector_type(4))) float f32x4;

static __device__ __forceinline__ short f2bf(float f) {
    __hip_bfloat16 h = __float2bfloat16(f);
    return *reinterpret_cast<short*>(&h);
}
static __device__ __forceinline__ float bf2f(short s) {
    union { unsigned u; float f; } v; v.u = ((unsigned)(unsigned short)s) << 16;
    return v.f;
}
static __device__ __forceinline__ bf16x8 cvt8(float4 a, float4 b) {
    bf16x8 r;
    r[0] = f2bf(a.x); r[1] = f2bf(a.y); r[2] = f2bf(a.z); r[3] = f2bf(a.w);
    r[4] = f2bf(b.x); r[5] = f2bf(b.y); r[6] = f2bf(b.z); r[7] = f2bf(b.w);
    return r;
}
static __device__ __forceinline__ unsigned pk2(float a, float b) {
    return (unsigned)(unsigned short)f2bf(a) | ((unsigned)(unsigned short)f2bf(b) << 16);
}
// LDS-only barrier: does NOT drain vmcnt.
static __device__ __forceinline__ void lds_barrier() {
    asm volatile("s_waitcnt lgkmcnt(0)" ::: "memory");
    __builtin_amdgcn_s_barrier();
}

// wbuf layout (shorts): WabT[256][128] @0 | W1cT[128][128] @32768 | W2T[128][128] @49152
//                       Wn1T[128][256] @65536 | Wn2T[128][128] @98304   (total 114688)
__global__ void prep_weights(const float* __restrict__ We1, const float* __restrict__ We2,
                             const float* __restrict__ Wn1, const float* __restrict__ Wn2,
                             short* __restrict__ wbuf) {
    int gid = blockIdx.x * 256 + threadIdx.x;
    if (gid < 32768) {
        int c = gid >> 7, k = gid & 127;
        float v = (c < 128) ? We1[k * 128 + c] : We1[(k + 128) * 128 + (c - 128)];
        wbuf[gid] = f2bf(v); return;
    }
    int g = gid - 32768;
    if (g < 16384) { int c = g >> 7, k = g & 127; wbuf[gid] = f2bf(We1[(k + 256) * 128 + c]); return; }
    g -= 16384;
    if (g < 16384) { int c = g >> 7, k = g & 127; wbuf[gid] = f2bf(We2[k * 128 + c]); return; }
    g -= 16384;
    if (g < 32768) { int c = g >> 8, k = g & 255; wbuf[gid] = f2bf(Wn1[k * 128 + c]); return; }
    g -= 32768;
    if (g < 16384) { int c = g >> 7, k = g & 127; wbuf[gid] = f2bf(Wn2[k * 128 + c]); }
}

// ---- CSR by dest (elist = edge ids sorted by dest) ----
__global__ void hist_kernel(const int* __restrict__ ei, int* __restrict__ cnt) {
    int t = blockIdx.x * 256 + threadIdx.x;
    if (t < Ee) atomicAdd(&cnt[ei[Ee + t]], 1);
}
__global__ void scan1(const int* __restrict__ cnt, int* __restrict__ cur, int* __restrict__ part) {
    __shared__ int s[256];
    int i = blockIdx.x * 256 + threadIdx.x;
    int v = (i < Nn) ? cnt[i] : 0;
    s[threadIdx.x] = v; __syncthreads();
    #pragma unroll
    for (int off = 1; off < 256; off <<= 1) {
        int u = (threadIdx.x >= off) ? s[threadIdx.x - off] : 0;
        __syncthreads(); s[threadIdx.x] += u; __syncthreads();
    }
    if (i < Nn) cur[i] = s[threadIdx.x] - v;
    if (threadIdx.x == 255) part[blockIdx.x] = s[255];
}
// parallel exclusive scan of the 196 block totals
__global__ void scan2(int* __restrict__ part) {
    __shared__ int s[256];
    int i = threadIdx.x;
    int v = (i < 196) ? part[i] : 0;
    s[i] = v; __syncthreads();
    #pragma unroll
    for (int off = 1; off < 256; off <<= 1) {
        int u = (i >= off) ? s[i - off] : 0;
        __syncthreads(); s[i] += u; __syncthreads();
    }
    if (i < 196) part[i] = s[i] - v;   // exclusive prefix
}
// scatter with fused global-offset add (scan3 folded in)
__global__ void scatter_k(const int* __restrict__ ei, int* __restrict__ cur,
                          const int* __restrict__ part, int* __restrict__ elist) {
    int t = blockIdx.x * 256 + threadIdx.x;
    if (t < Ee) {
        int d = ei[Ee + t];
        int pos = part[d >> 8] + atomicAdd(&cur[d], 1);
        elist[pos] = t;
    }
}

// ---- node_pre: xa = x@W1a, xb = x@W1b (bf16 out, no bias) ----
__global__ __launch_bounds__(256) void node_pre(
    const float* __restrict__ x, const short* __restrict__ WabT,
    short* __restrict__ xa, short* __restrict__ xb)
{
    __shared__ __align__(16) short X[32 * 128];

    const int nbase = blockIdx.x * 32;
    const int t = threadIdx.x;
    const int wv = t >> 6, lane = t & 63;
    const int row16 = lane & 15, kg = lane >> 4;

    {
        int g = t >> 3, q = t & 7;
        const float* src = x + ((size_t)(nbase + g)) * Hd + q * 16;
        float4 a0 = ((const float4*)src)[0], a1 = ((const float4*)src)[1];
        float4 a2 = ((const float4*)src)[2], a3 = ((const float4*)src)[3];
        ((bf16x8*)X)[g * 16 + ((q * 2) ^ (g & 7))]     = cvt8(a0, a1);
        ((bf16x8*)X)[g * 16 + ((q * 2 + 1) ^ (g & 7))] = cvt8(a2, a3);
    }

    bf16x8 wf[4][4];
    #pragma unroll
    for (int nt = 0; nt < 4; nt++) {
        int n = wv * 64 + nt * 16 + row16;
        #pragma unroll
        for (int kt = 0; kt < 4; kt++)
            wf[kt][nt] = *(const bf16x8*)(WabT + n * 128 + kt * 32 + kg * 8);
    }
    __syncthreads();

    f32x4 acc[2][4];
    #pragma unroll
    for (int mt = 0; mt < 2; mt++)
        #pragma unroll
        for (int nt = 0; nt < 4; nt++) acc[mt][nt] = (f32x4){0.f,0.f,0.f,0.f};

    #pragma unroll
    for (int mt = 0; mt < 2; mt++) {
        int row = mt * 16 + row16;
        #pragma unroll
        for (int kt = 0; kt < 4; kt++) {
            bf16x8 xf = ((const bf16x8*)X)[row * 16 + ((kt * 4 + kg) ^ (row & 7))];
            #pragma unroll
            for (int nt = 0; nt < 4; nt++)
                acc[mt][nt] = __builtin_amdgcn_mfma_f32_16x16x32_bf16(wf[kt][nt], xf, acc[mt][nt], 0, 0, 0);
        }
    }

    #pragma unroll
    for (int mt = 0; mt < 2; mt++) {
        size_t node = nbase + mt * 16 + row16;
        #pragma unroll
        for (int nt = 0; nt < 4; nt++) {
            int ch = wv * 64 + nt * 16 + kg * 4;
            uint2 pk = { pk2(acc[mt][nt][0], acc[mt][nt][1]), pk2(acc[mt][nt][2], acc[mt][nt][3]) };
            short* dst = (ch < 128) ? (xa + node * Hd + ch) : (xb + node * Hd + (ch - 128));
            *(uint2*)dst = pk;
        }
    }
}

// ---- edge_mlp: 128-edge DEST-SORTED tiles (r10/r14 structure, best known) ----
__global__ __launch_bounds__(512) void edge_mlp(
    const float* __restrict__ ea, const int* __restrict__ ei,
    const int* __restrict__ elist,
    const short* __restrict__ xa, const short* __restrict__ xb,
    const short* __restrict__ W1cT, const float* __restrict__ be1,
    const short* __restrict__ W2T, const float* __restrict__ be2,
    float* __restrict__ e_out, float* __restrict__ agg)
{
    __shared__ __align__(16) char smem[65536 + 1536];
    short* Aea = (short*)smem;                     // [128 rows][16 groups]
    short* A2  = (short*)(smem + 32768);           // [128 rows][16 groups]
    int* ol = (int*)(smem + 65536);                // [128]
    int* sl = ol + 128;
    int* dl = sl + 128;

    const int orig = blockIdx.x;
    const int q = NT2 / 8, rr = NT2 % 8;
    const int xcd = orig & 7, idx = orig >> 3;
    const int tile = (xcd < rr ? xcd * (q + 1) : rr * (q + 1) + (xcd - rr) * q) + idx;

    const int b = tile / TPB2;
    const int w0 = (tile % TPB2) * 128;
    const int t = threadIdx.x;
    const int wv = t >> 6, lane = t & 63;
    const int row16 = lane & 15, kg = lane >> 4;
    const int n0 = wv * 16 + kg * 4;
    const int sr = t >> 3, sq = t & 7;

    if (t < 128) {
        int o = elist[w0 + t];
        ol[t] = o; sl[t] = ei[o]; dl[t] = ei[Ee + o];
    }
    __syncthreads();

    int on[8], sn[8], dn[8];
    #pragma unroll
    for (int mt = 0; mt < 8; mt++) {
        int r = mt * 16 + row16;
        on[mt] = ol[r]; sn[mt] = sl[r]; dn[mt] = dl[r];
    }

    #pragma unroll
    for (int h = 0; h < 2; h++) {
        int row = sr + h * 64;
        const float* src = ea + ((size_t)b * Ee + ol[row]) * Hd + sq * 16;
        float4 a0 = ((const float4*)src)[0], a1 = ((const float4*)src)[1];
        float4 a2 = ((const float4*)src)[2], a3 = ((const float4*)src)[3];
        ((bf16x8*)Aea)[row * 16 + ((sq * 2) ^ (row & 7))]     = cvt8(a0, a1);
        ((bf16x8*)Aea)[row * 16 + ((sq * 2 + 1) ^ (row & 7))] = cvt8(a2, a3);
    }

    bf16x8 w1[4], w2[4];
    {
        const short* wp1 = W1cT + (wv * 16 + row16) * 128 + kg * 8;
        const short* wp2 = W2T  + (wv * 16 + row16) * 128 + kg * 8;
        #pragma unroll
        for (int kt = 0; kt < 4; kt++) {
            w1[kt] = *(const bf16x8*)(wp1 + kt * 32);
            w2[kt] = *(const bf16x8*)(wp2 + kt * 32);
        }
    }
    bf16x4 av[8], bv[8];
    #pragma unroll
    for (int mt = 0; mt < 8; mt++) {
        av[mt] = *(const bf16x4*)(xa + ((size_t)b * Nn + sn[mt]) * Hd + n0);
        bv[mt] = *(const bf16x4*)(xb + ((size_t)b * Nn + dn[mt]) * Hd + n0);
    }
    const float4 b1v = *(const float4*)(be1 + n0);
    const float4 b2v = *(const float4*)(be2 + n0);
    lds_barrier();

    // L1 GEMM
    f32x4 acc[8];
    #pragma unroll
    for (int mt = 0; mt < 8; mt++) acc[mt] = (f32x4){0.f,0.f,0.f,0.f};
    #pragma unroll
    for (int kt = 0; kt < 4; kt++) {
        #pragma unroll
        for (int mt = 0; mt < 8; mt++) {
            int row = mt * 16 + row16;
            bf16x8 af = ((const bf16x8*)Aea)[row * 16 + ((kt * 4 + kg) ^ (row & 7))];
            acc[mt] = __builtin_amdgcn_mfma_f32_16x16x32_bf16(w1[kt], af, acc[mt], 0, 0, 0);
        }
    }

    // epilogue -> A2 (separate region, no barrier needed)
    #pragma unroll
    for (int mt = 0; mt < 8; mt++) {
        int row = mt * 16 + row16;
        float vv[4];
        #pragma unroll
        for (int r = 0; r < 4; r++) {
            float u = acc[mt][r] + b1v[r] + bf2f(av[mt][r]) + bf2f(bv[mt][r]);
            vv[r] = u > 0.f ? u : 0.f;
        }
        int G = (n0 >> 3) ^ (row & 7);
        *(uint2*)((char*)A2 + row * 256 + G * 16 + (n0 & 7) * 2) =
            (uint2){ pk2(vv[0], vv[1]), pk2(vv[2], vv[3]) };
    }
    lds_barrier();

    // L2 GEMM (reuse acc)
    #pragma unroll
    for (int mt = 0; mt < 8; mt++) acc[mt] = (f32x4){0.f,0.f,0.f,0.f};
    #pragma unroll
    for (int kt = 0; kt < 4; kt++) {
        #pragma unroll
        for (int mt = 0; mt < 8; mt++) {
            int row = mt * 16 + row16;
            bf16x8 hf = *(const bf16x8*)((const char*)A2 + row * 256 + (((kt * 4 + kg) ^ (row & 7)) * 16));
            acc[mt] = __builtin_amdgcn_mfma_f32_16x16x32_bf16(w2[kt], hf, acc[mt], 0, 0, 0);
        }
    }

    #pragma unroll
    for (int mt = 0; mt < 8; mt++) {
        acc[mt][0] += b2v.x; acc[mt][1] += b2v.y;
        acc[mt][2] += b2v.z; acc[mt][3] += b2v.w;
        float4 ov = { acc[mt][0], acc[mt][1], acc[mt][2], acc[mt][3] };
        *(float4*)(e_out + ((size_t)b * Ee + on[mt]) * Hd + n0) = ov;
    }
    lds_barrier();

    // restage e-tile f32 into et[128][512B]
    #pragma unroll
    for (int mt = 0; mt < 8; mt++) {
        int row = mt * 16 + row16;
        float4 ov = { acc[mt][0], acc[mt][1], acc[mt][2], acc[mt][3] };
        *(float4*)(smem + row * 512 + (((n0 >> 2) ^ (row & 7)) << 4)) = ov;
    }
    lds_barrier();

    // segment-sum over sorted dests -> few atomics
    {
        int c = t & 127, rg2 = t >> 7;
        int g_c = c >> 2, sub = (c & 3) << 2;
        int base = rg2 * 32;
        float s = 0.f;
        int pd = dl[base];
        #pragma unroll
        for (int i = 0; i < 32; i++) {
            int row = base + i;
            float v = *(const float*)(smem + row * 512 + ((g_c ^ (row & 7)) << 4) + sub);
            int d = dl[row];
            if (d != pd) {
                unsafeAtomicAdd(agg + ((size_t)b * Nn + pd) * Hd + c, s);
                s = 0.f; pd = d;
            }
            s += v;
        }
        unsafeAtomicAdd(agg + ((size_t)b * Nn + pd) * Hd + c, s);
    }
}

// ---- node_mlp (streaming, 64-node tiles): x_out = relu(concat(x,agg)@Wn1+bn1)@Wn2+bn2 ----
__global__ __launch_bounds__(512) void node_mlp(
    const float* __restrict__ x, const float* __restrict__ agg,
    const short* __restrict__ Wn1T, const float* __restrict__ bn1,
    const short* __restrict__ Wn2T, const float* __restrict__ bn2,
    float* __restrict__ xout)
{
    __shared__ __align__(16) short A[64 * 256];      // 32KB: [node][32 groups] (x | agg)
    __shared__ __align__(16) short A2[64 * 128];     // 16KB hidden

    const int tilesPerB = (Nn + 63) / 64;            // 782
    const int bid = blockIdx.x;
    const int b = bid / tilesPerB;
    const int nbase = (bid % tilesPerB) * 64;
    const int t = threadIdx.x;
    const int wv = t >> 6, lane = t & 63;
    const int row16 = lane & 15, kg = lane >> 4;
    const int n0 = wv * 16 + kg * 4;

    // stage: 8 threads per node, 16 floats (64B) each from x and agg
    {
        int g = t >> 3, q = t & 7;
        int n = nbase + g;
        int nc_ = n < Nn ? n : Nn - 1;
        const float* xr = x + ((size_t)b * Nn + nc_) * Hd + q * 16;
        float4 x0 = ((const float4*)xr)[0], x1 = ((const float4*)xr)[1];
        float4 x2 = ((const float4*)xr)[2], x3 = ((const float4*)xr)[3];
        const float* ar = agg + ((size_t)b * Nn + nc_) * Hd + q * 16;
        float4 s0 = ((const float4*)ar)[0], s1 = ((const float4*)ar)[1];
        float4 s2 = ((const float4*)ar)[2], s3 = ((const float4*)ar)[3];
        ((bf16x8*)A)[g * 32 + ((q * 2) ^ (g & 7))]          = cvt8(x0, x1);
        ((bf16x8*)A)[g * 32 + ((q * 2 + 1) ^ (g & 7))]      = cvt8(x2, x3);
        ((bf16x8*)A)[g * 32 + ((16 + q * 2) ^ (g & 7))]     = cvt8(s0, s1);
        ((bf16x8*)A)[g * 32 + ((16 + q * 2 + 1) ^ (g & 7))] = cvt8(s2, s3);
    }

    bf16x8 w1[8];
    {
        const short* wp = Wn1T + (wv * 16 + row16) * 256 + kg * 8;
        #pragma unroll
        for (int kt = 0; kt < 8; kt++) w1[kt] = *(const bf16x8*)(wp + kt * 32);
    }
    const float4 b1v = *(const float4*)(bn1 + n0);
    lds_barrier();

    // L1 GEMM K=256, 4 row-groups
    f32x4 acc[4];
    #pragma unroll
    for (int mt = 0; mt < 4; mt++) acc[mt] = (f32x4){0.f,0.f,0.f,0.f};
    #pragma unroll
    for (int kt = 0; kt < 8; kt++) {
        #pragma unroll
        for (int mt = 0; mt < 4; mt++) {
            int row = mt * 16 + row16;
            bf16x8 af = ((const bf16x8*)A)[row * 32 + ((kt * 4 + kg) ^ (row & 7))];
            acc[mt] = __builtin_amdgcn_mfma_f32_16x16x32_bf16(w1[kt], af, acc[mt], 0, 0, 0);
        }
    }

    bf16x8 w2[4];
    {
        const short* wp = Wn2T + (wv * 16 + row16) * 128 + kg * 8;
        #pragma unroll
        for (int kt = 0; kt < 4; kt++) w2[kt] = *(const bf16x8*)(wp + kt * 32);
    }

    #pragma unroll
    for (int mt = 0; mt < 4; mt++) {
        int row = mt * 16 + row16;
        float v[4];
        #pragma unroll
        for (int r = 0; r < 4; r++) {
            float u = acc[mt][r] + b1v[r];
            v[r] = u > 0.f ? u : 0.f;
        }
        int G = (n0 >> 3) ^ (row & 7);
        *(uint2*)((char*)A2 + row * 256 + G * 16 + (n0 & 7) * 2) = (uint2){ pk2(v[0], v[1]), pk2(v[2], v[3]) };
    }
    lds_barrier();

    // L2 GEMM K=128 (reuse acc)
    #pragma unroll
    for (int mt = 0; mt < 4; mt++) acc[mt] = (f32x4){0.f,0.f,0.f,0.f};
    #pragma unroll
    for (int kt = 0; kt < 4; kt++) {
        #pragma unroll
        for (int mt = 0; mt < 4; mt++) {
            int row = mt * 16 + row16;
            bf16x8 hf = *(const bf16x8*)((const char*)A2 + row * 256 + (((kt * 4 + kg) ^ (row & 7)) * 16));
            acc[mt] = __builtin_amdgcn_mfma_f32_16x16x32_bf16(w2[kt], hf, acc[mt], 0, 0, 0);
        }
    }
    const float4 b2v = *(const float4*)(bn2 + n0);
    #pragma unroll
    for (int mt = 0; mt < 4; mt++) {
        int node = nbase + mt * 16 + row16;
        if (node < Nn) {
            float4 ov;
            ov.x = acc[mt][0] + b2v.x;
            ov.y = acc[mt][1] + b2v.y;
            ov.z = acc[mt][2] + b2v.z;
            ov.w = acc[mt][3] + b2v.w;
            *(float4*)(xout + ((size_t)b * Nn + node) * Hd + n0) = ov;
        }
    }
}

extern "C" void kernel_launch(void* const* d_in, const int* in_sizes, int n_in,
                              void* d_out, int out_size, void* d_ws, size_t ws_size,
                              hipStream_t stream) {
    const float* x   = (const float*)d_in[0];
    const int*   ei  = (const int*)d_in[1];
    const float* ea  = (const float*)d_in[2];
    const float* We1 = (const float*)d_in[3];
    const float* be1 = (const float*)d_in[4];
    const float* We2 = (const float*)d_in[5];
    const float* be2 = (const float*)d_in[6];
    const float* Wn1 = (const float*)d_in[7];
    const float* bn1 = (const float*)d_in[8];
    const float* Wn2 = (const float*)d_in[9];
    const float* bn2 = (const float*)d_in[10];

    float* xout  = (float*)d_out;
    float* e_out = xout + (size_t)Bb * Nn * Hd;     // outputs: x_out, then e

    // ws layout: wbuf | xa | xb | agg(f32) | cnt | cur | part | elist
    char* w = (char*)d_ws;
    short* wbuf  = (short*)w;                               // 229376 B
    short* xa    = (short*)(w + 229376);                    // 25.6 MB
    short* xb    = xa + (size_t)NROWS * Hd;                 // 25.6 MB
    float* agg   = (float*)(xb + (size_t)NROWS * Hd);       // 51.2 MB
    int*   cnt   = (int*)(agg + (size_t)Bb * Nn * Hd);
    int*   cur   = cnt + Nn;
    int*   part  = cur + Nn;                                // 256
    int*   elist = part + 256;                              // Ee

    hipMemsetAsync(cnt, 0, Nn * sizeof(int), stream);
    hipMemsetAsync(agg, 0, (size_t)Bb * Nn * Hd * sizeof(float), stream);

    prep_weights<<<448, 256, 0, stream>>>(We1, We2, Wn1, Wn2, wbuf);
    hist_kernel<<<(Ee + 255) / 256, 256, 0, stream>>>(ei, cnt);
    scan1<<<196, 256, 0, stream>>>(cnt, cur, part);
    scan2<<<1, 256, 0, stream>>>(part);
    scatter_k<<<(Ee + 255) / 256, 256, 0, stream>>>(ei, cur, part, elist);

    node_pre<<<NROWS / 32, 256, 0, stream>>>(x, wbuf, xa, xb);

    edge_mlp<<<NT2, 512, 0, stream>>>(
        ea, ei, elist, xa, xb, wbuf + 32768, be1, wbuf + 49152, be2, e_out, agg);

    node_mlp<<<Bb * ((Nn + 63) / 64), 512, 0, stream>>>(
        x, agg, wbuf + 65536, bn1, wbuf + 98304, bn2, xout);
}